// Round 5
// baseline (1181.448 us; speedup 1.0000x reference)
//
#include <hip/hip_runtime.h>
#include <math.h>

#define NNODE 200000
#define NEDGE 1000000
#define HEDGE 500000

typedef __attribute__((ext_vector_type(8))) short bf16x8;
typedef __attribute__((ext_vector_type(4))) float f32x4;

// ---- float <-> bf16 (RNE) ----
__device__ __forceinline__ unsigned short f2bf(float f) {
  unsigned u = __float_as_uint(f);
  unsigned r = (u + 0x7fffu + ((u >> 16) & 1u)) >> 16;
  return (unsigned short)r;
}
__device__ __forceinline__ float bf2f(unsigned short h) {
  return __uint_as_float(((unsigned)h) << 16);
}

// ======================= CSR build =======================
// A: all edges bucketed by dst (for aggr). B: c2l edges bucketed by src
// (for LSE); listB stores the edge's dst node (the emb row to read).
__global__ void k_deg(const int* __restrict__ ei, const int* __restrict__ c2li,
                      int* __restrict__ degA, int* __restrict__ degB) {
  int j = blockIdx.x * 256 + threadIdx.x;
  if (j < NEDGE) atomicAdd(&degA[ei[2 * j + 1]], 1);
  if (j < HEDGE) {
    int jj = c2li[j];
    atomicAdd(&degB[ei[2 * jj]], 1);
  }
}

// Two blocks: block 0 scans degA, block 1 scans degB. 1024 threads, each
// owning a 196-element chunk; LDS Hillis-Steele over the 1024 partials.
__global__ void __launch_bounds__(1024)
k_scan(const int* __restrict__ degA, int* __restrict__ offA, int* __restrict__ curA,
       const int* __restrict__ degB, int* __restrict__ offB, int* __restrict__ curB) {
  const int* deg = blockIdx.x ? degB : degA;
  int* off = blockIdx.x ? offB : offA;
  int* cur = blockIdx.x ? curB : curA;
  __shared__ int part[1024];
  int t = threadIdx.x;
  const int CH = (NNODE + 1023) / 1024;  // 196
  int lo = t * CH, hi = min(lo + CH, NNODE);
  int sum = 0;
  for (int i = lo; i < hi; ++i) sum += deg[i];
  part[t] = sum;
  __syncthreads();
  for (int d = 1; d < 1024; d <<= 1) {
    int add = (t >= d) ? part[t - d] : 0;
    __syncthreads();
    part[t] += add;
    __syncthreads();
  }
  int base = part[t] - sum;  // exclusive prefix
  for (int i = lo; i < hi; ++i) {
    off[i] = base; cur[i] = base;
    base += deg[i];
  }
}

__global__ void k_fill(const int* __restrict__ ei, const int* __restrict__ c2li,
                       int* __restrict__ curA, int* __restrict__ listA,
                       int* __restrict__ curB, int* __restrict__ listB) {
  int j = blockIdx.x * 256 + threadIdx.x;
  if (j < NEDGE) {
    int d = ei[2 * j + 1];
    int s = atomicAdd(&curA[d], 1);
    listA[s] = j;
  }
  if (j < HEDGE) {
    int jj = c2li[j];
    int sn = ei[2 * jj], dn = ei[2 * jj + 1];
    int s = atomicAdd(&curB[sn], 1);
    listB[s] = dn;
  }
}

// ---- per-node gather sum: aggr[n] = sum of emb rows of in-edges ----
__global__ void k_aggr_g(const int* __restrict__ off, const int* __restrict__ deg,
                         const int* __restrict__ list, const float* __restrict__ emb,
                         float* __restrict__ aggr) {
  int w = blockIdx.x * 4 + (threadIdx.x >> 6);
  int c = threadIdx.x & 63;
  if (w >= NNODE) return;
  int o = off[w], n = deg[w];
  float s = 0.f;
  for (int i = 0; i < n; ++i) {
    int e = list[o + i];
    s += emb[(size_t)e * 64 + c];
  }
  aggr[(size_t)w * 64 + c] = s;  // empty nodes -> 0 (they may be read via l2c_src)
}

// ---- per-node fused online LSE over emb[dst] rows of its c2l out-edges ----
__global__ void k_lse_g(const int* __restrict__ off, const int* __restrict__ deg,
                        const int* __restrict__ list, const float* __restrict__ emb,
                        float* __restrict__ lse) {
  int w = blockIdx.x * 4 + (threadIdx.x >> 6);
  int c = threadIdx.x & 63;
  if (w >= NNODE) return;
  int o = off[w], n = deg[w];
  if (n == 0) return;  // lse only ever read at nodes with c2l out-edges
  float m = -INFINITY, s = 0.f;
  for (int i = 0; i < n; ++i) {
    int d = list[o + i];
    float v = emb[(size_t)d * 64 + c];
    float nm = fmaxf(m, v);
    s = s * __expf(m - nm) + __expf(v - nm);
    m = nm;
  }
  lse[(size_t)w * 64 + c] = __logf(s) + m;  // s >= 1 here
}

// ======================= weight prep =======================
// Frag-ordered bf16 hi/lo. value = W[32s + 8*(lane>>4) + j][16c + (lane&15)].
// Elem offsets: l2c L1/L2/L3: 0/4096/8192; merge_W0: 12288 (K=128);
// merge_W L1/L2: 20480/24576; c2l L1/L2/L3: 28672/32768/36864. Total 40960.
__global__ void k_prepw(const float* __restrict__ l2cW, const float* __restrict__ mW0,
                        const float* __restrict__ mW, const float* __restrict__ c2lW,
                        unsigned short* __restrict__ WH, unsigned short* __restrict__ WL) {
  int tid = blockIdx.x * 256 + threadIdx.x;
  if (tid >= 40960) return;
  const float* src;
  int base;
  if (tid < 12288) {
    int m = tid / 4096; src = l2cW + m * 4096; base = m * 4096;
  } else if (tid < 20480) {
    src = mW0; base = 12288;
  } else if (tid < 28672) {
    int m = (tid - 20480) / 4096; src = mW + m * 4096; base = 20480 + m * 4096;
  } else {
    int m = (tid - 28672) / 4096; src = c2lW + m * 4096; base = 28672 + m * 4096;
  }
  int local = tid - base;
  int f = local >> 9;           // frag id = s*4+c
  int l = (local >> 3) & 63;    // lane
  int j = local & 7;            // elem
  int s = f >> 2, c = f & 3;
  int k = 32 * s + 8 * (l >> 4) + j;
  int col = 16 * c + (l & 15);
  float v = src[k * 64 + col];
  unsigned short hh = f2bf(v);
  WH[tid] = hh;
  WL[tid] = f2bf(v - bf2f(hh));
}

// ======================= MFMA MLP machinery =======================
// Wave-private LDS tile xs[16 rows][64 cols] f32, XOR-swizzled:
//   dword(row,col) = row*64 + (((col>>2) ^ row) & 15)*4 + (col & 3)

__device__ __forceinline__ void split8(float t0, float t1, float t2, float t3,
                                       float t4, float t5, float t6, float t7,
                                       bf16x8& ah, bf16x8& al) {
  unsigned short h;
  h = f2bf(t0); ah[0] = (short)h; al[0] = (short)f2bf(t0 - bf2f(h));
  h = f2bf(t1); ah[1] = (short)h; al[1] = (short)f2bf(t1 - bf2f(h));
  h = f2bf(t2); ah[2] = (short)h; al[2] = (short)f2bf(t2 - bf2f(h));
  h = f2bf(t3); ah[3] = (short)h; al[3] = (short)f2bf(t3 - bf2f(h));
  h = f2bf(t4); ah[4] = (short)h; al[4] = (short)f2bf(t4 - bf2f(h));
  h = f2bf(t5); ah[5] = (short)h; al[5] = (short)f2bf(t5 - bf2f(h));
  h = f2bf(t6); ah[6] = (short)h; al[6] = (short)f2bf(t6 - bf2f(h));
  h = f2bf(t7); ah[7] = (short)h; al[7] = (short)f2bf(t7 - bf2f(h));
}

// Split-bf16: acc += al*wh + ah*wl + ah*wh (misses only lo*lo ~ 2^-18).
template <int NS, bool RELU, bool FLIP>
__device__ __forceinline__ void mfma_layer(const float* xw, int lane,
                                           const unsigned short* __restrict__ wh_,
                                           const unsigned short* __restrict__ wl_,
                                           const float* __restrict__ bias, f32x4 (&acc)[4]) {
  int col15 = lane & 15, hq = lane >> 4;
#pragma unroll
  for (int c = 0; c < 4; ++c) {
    float bv = bias[16 * c + col15];
    acc[c] = (f32x4){bv, bv, bv, bv};
  }
#pragma unroll
  for (int s = 0; s < NS; ++s) {
    int flip = (FLIP && s >= NS / 2);
    int arow = flip ? (col15 ^ 1) : col15;
    int ks = flip ? (s - NS / 2) : s;
    const float* xr = xw + arow * 64;
    float4 A0 = *(const float4*)(xr + ((((8 * ks + 2 * hq + 0) ^ arow) & 15) << 2));
    float4 A1 = *(const float4*)(xr + ((((8 * ks + 2 * hq + 1) ^ arow) & 15) << 2));
    bf16x8 ah, al;
    split8(A0.x, A0.y, A0.z, A0.w, A1.x, A1.y, A1.z, A1.w, ah, al);
#pragma unroll
    for (int c = 0; c < 4; ++c) {
      const unsigned short* wo = wh_ + ((size_t)((s * 4 + c) * 64 + lane) * 8);
      const unsigned short* lo = wl_ + ((size_t)((s * 4 + c) * 64 + lane) * 8);
      bf16x8 wh = *(const bf16x8*)wo;
      bf16x8 wl = *(const bf16x8*)lo;
      acc[c] = __builtin_amdgcn_mfma_f32_16x16x32_bf16(al, wh, acc[c], 0, 0, 0);
      acc[c] = __builtin_amdgcn_mfma_f32_16x16x32_bf16(ah, wl, acc[c], 0, 0, 0);
      acc[c] = __builtin_amdgcn_mfma_f32_16x16x32_bf16(ah, wh, acc[c], 0, 0, 0);
    }
  }
  if (RELU) {
#pragma unroll
    for (int c = 0; c < 4; ++c)
#pragma unroll
      for (int r = 0; r < 4; ++r) acc[c][r] = fmaxf(acc[c][r], 0.f);
  }
}

__device__ __forceinline__ void commitA(float* xw, int lane, const f32x4 (&acc)[4]) {
  int col15 = lane & 15, hq = lane >> 4;
#pragma unroll
  for (int c = 0; c < 4; ++c)
#pragma unroll
    for (int r = 0; r < 4; ++r) {
      int row = 4 * hq + r, col = 16 * c + col15;
      xw[row * 64 + ((((col >> 2) ^ row) & 15) << 2) + (col & 3)] = acc[c][r];
    }
}

// ---- l2c: 3-layer MLP -> pair merge (K=128, flip) -> 2-layer MLP ----
__global__ void __launch_bounds__(256, 4)
k_l2c(const int* __restrict__ ei, const int* __restrict__ l2ci,
      const float* __restrict__ emb, const float* __restrict__ aggr,
      const unsigned short* __restrict__ WH, const unsigned short* __restrict__ WL,
      const float* __restrict__ l2cb, const float* __restrict__ mb0,
      const float* __restrict__ mb, float* __restrict__ out) {
  __shared__ float xs[4][1024];
  int lane = threadIdx.x & 63, w = threadIdx.x >> 6;
  float* xw = xs[w];
  int rbase = (blockIdx.x * 4 + w) * 16;
  int col15 = lane & 15, hq = lane >> 4;
  int rin = min(rbase + col15, HEDGE - 1);
  int j = l2ci[rin];
  int sN = ei[2 * j], dN = ei[2 * j + 1];
  const float* ap = aggr + (size_t)sN * 64 + 16 * hq;
  const float* ep = emb + (size_t)dN * 64 + 16 * hq;
#pragma unroll
  for (int q = 0; q < 4; ++q) {
    float4 a = *(const float4*)(ap + 4 * q);
    float4 e = *(const float4*)(ep + 4 * q);
    float4 v = {a.x - e.x, a.y - e.y, a.z - e.z, a.w - e.w};
    *(float4*)(xw + col15 * 64 + ((((4 * hq + q) ^ col15) & 15) << 2)) = v;
  }
  f32x4 acc[4];
  mfma_layer<2, true, false>(xw, lane, WH, WL, l2cb, acc);                     commitA(xw, lane, acc);
  mfma_layer<2, true, false>(xw, lane, WH + 4096, WL + 4096, l2cb + 64, acc);  commitA(xw, lane, acc);
  mfma_layer<2, false, false>(xw, lane, WH + 8192, WL + 8192, l2cb + 128, acc); commitA(xw, lane, acc);
  mfma_layer<4, true, true>(xw, lane, WH + 12288, WL + 12288, mb0, acc);       commitA(xw, lane, acc);
  mfma_layer<2, true, false>(xw, lane, WH + 20480, WL + 20480, mb, acc);       commitA(xw, lane, acc);
  mfma_layer<2, false, false>(xw, lane, WH + 24576, WL + 24576, mb + 64, acc);
  int jo[4];
#pragma unroll
  for (int r = 0; r < 4; ++r) {
    int rr = rbase + 4 * hq + r;
    jo[r] = (rr < HEDGE) ? l2ci[rr] : -1;
  }
#pragma unroll
  for (int c = 0; c < 4; ++c)
#pragma unroll
    for (int r = 0; r < 4; ++r)
      if (jo[r] >= 0) out[(size_t)jo[r] * 64 + 16 * c + col15] = acc[c][r];
}

// ---- c2l: 3-layer MLP on (lse[src] - e) ----
__global__ void __launch_bounds__(256, 4)
k_c2l(const int* __restrict__ ei, const int* __restrict__ c2li,
      const float* __restrict__ emb, const float* __restrict__ lse,
      const unsigned short* __restrict__ WH, const unsigned short* __restrict__ WL,
      const float* __restrict__ c2lb, float* __restrict__ out) {
  __shared__ float xs[4][1024];
  int lane = threadIdx.x & 63, w = threadIdx.x >> 6;
  float* xw = xs[w];
  int rbase = (blockIdx.x * 4 + w) * 16;
  int col15 = lane & 15, hq = lane >> 4;
  int rin = min(rbase + col15, HEDGE - 1);
  int j = c2li[rin];
  int sN = ei[2 * j], dN = ei[2 * j + 1];
  const float* ap = lse + (size_t)sN * 64 + 16 * hq;
  const float* ep = emb + (size_t)dN * 64 + 16 * hq;
#pragma unroll
  for (int q = 0; q < 4; ++q) {
    float4 a = *(const float4*)(ap + 4 * q);
    float4 e = *(const float4*)(ep + 4 * q);
    float4 v = {a.x - e.x, a.y - e.y, a.z - e.z, a.w - e.w};
    *(float4*)(xw + col15 * 64 + ((((4 * hq + q) ^ col15) & 15) << 2)) = v;
  }
  f32x4 acc[4];
  mfma_layer<2, true, false>(xw, lane, WH + 28672, WL + 28672, c2lb, acc);       commitA(xw, lane, acc);
  mfma_layer<2, true, false>(xw, lane, WH + 32768, WL + 32768, c2lb + 64, acc);  commitA(xw, lane, acc);
  mfma_layer<2, false, false>(xw, lane, WH + 36864, WL + 36864, c2lb + 128, acc);
  int jo[4];
#pragma unroll
  for (int r = 0; r < 4; ++r) {
    int rr = rbase + 4 * hq + r;
    jo[r] = (rr < HEDGE) ? c2li[rr] : -1;
  }
#pragma unroll
  for (int c = 0; c < 4; ++c)
#pragma unroll
    for (int r = 0; r < 4; ++r)
      if (jo[r] >= 0) out[(size_t)jo[r] * 64 + 16 * c + col15] = acc[c][r];
}

extern "C" void kernel_launch(void* const* d_in, const int* in_sizes, int n_in,
                              void* d_out, int out_size, void* d_ws, size_t ws_size,
                              hipStream_t stream) {
  const int* ei = (const int*)d_in[0];
  const int* l2ci = (const int*)d_in[1];
  const int* c2li = (const int*)d_in[2];
  const float* emb = (const float*)d_in[3];
  const float* l2cW = (const float*)d_in[4];
  const float* l2cb = (const float*)d_in[5];
  const float* c2lW = (const float*)d_in[6];
  const float* c2lb = (const float*)d_in[7];
  const float* mW0 = (const float*)d_in[8];
  const float* mb0 = (const float*)d_in[9];
  const float* mW = (const float*)d_in[10];
  const float* mb = (const float*)d_in[11];
  float* out = (float*)d_out;

  char* ws = (char*)d_ws;
  const size_t NB = (size_t)NNODE * 64 * 4;  // 51.2 MB per node-buffer
  float* aggr = (float*)ws;
  float* lse = (float*)(ws + NB);
  unsigned short* WH = (unsigned short*)(ws + 2 * NB);
  unsigned short* WL = WH + 40960;  // 163840 B total for weights
  char* p = ws + 2 * NB + 163840;
  int* degA = (int*)p; p += NNODE * 4;
  int* degB = (int*)p; p += NNODE * 4;
  int* offA = (int*)p; p += NNODE * 4;
  int* offB = (int*)p; p += NNODE * 4;
  int* curA = (int*)p; p += NNODE * 4;
  int* curB = (int*)p; p += NNODE * 4;
  int* listA = (int*)p; p += (size_t)NEDGE * 4;
  int* listB = (int*)p; p += (size_t)HEDGE * 4;

  hipMemsetAsync(degA, 0, 2 * NNODE * 4, stream);  // degA+degB contiguous

  dim3 B(256);
  int gE = (NEDGE + 255) / 256;
  k_deg<<<gE, B, 0, stream>>>(ei, c2li, degA, degB);
  k_scan<<<2, 1024, 0, stream>>>(degA, offA, curA, degB, offB, curB);
  k_fill<<<gE, B, 0, stream>>>(ei, c2li, curA, listA, curB, listB);
  k_prepw<<<160, B, 0, stream>>>(l2cW, mW0, mW, c2lW, WH, WL);
  int gN = (NNODE + 3) / 4;
  k_aggr_g<<<gN, B, 0, stream>>>(offA, degA, listA, emb, aggr);
  k_lse_g<<<gN, B, 0, stream>>>(offB, degB, listB, emb, lse);
  int gmlp = (HEDGE / 16 + 3) / 4;
  k_l2c<<<gmlp, B, 0, stream>>>(ei, l2ci, emb, aggr, WH, WL, l2cb, mb0, mb, out);
  k_c2l<<<gmlp, B, 0, stream>>>(ei, c2li, emb, lse, WH, WL, c2lb, out);
}

// Round 6
// 813.667 us; speedup vs baseline: 1.4520x; 1.4520x over previous
//
#include <hip/hip_runtime.h>
#include <math.h>

#define NNODE 200000
#define NEDGE 1000000
#define HEDGE 500000

typedef __attribute__((ext_vector_type(8))) short bf16x8;
typedef __attribute__((ext_vector_type(4))) float f32x4;

// ---- float <-> bf16 (RNE) ----
__device__ __forceinline__ unsigned short f2bf(float f) {
  unsigned u = __float_as_uint(f);
  unsigned r = (u + 0x7fffu + ((u >> 16) & 1u)) >> 16;
  return (unsigned short)r;
}
__device__ __forceinline__ float bf2f(unsigned short h) {
  return __uint_as_float(((unsigned)h) << 16);
}

// ======================= CSR build =======================
// A: all edges bucketed by dst (for aggr). B: c2l edges bucketed by src
// (for LSE); listB stores the edge's dst node (the emb row to read).
__global__ void k_deg(const int* __restrict__ ei, const int* __restrict__ c2li,
                      int* __restrict__ degA, int* __restrict__ degB) {
  int j = blockIdx.x * 256 + threadIdx.x;
  if (j < NEDGE) atomicAdd(&degA[ei[2 * j + 1]], 1);
  if (j < HEDGE) {
    int jj = c2li[j];
    atomicAdd(&degB[ei[2 * jj]], 1);
  }
}

// Wave-aggregated CSR range allocator: bucket ORDER is irrelevant for the
// gather kernels, so skip the global prefix scan entirely. Each wave does a
// 64-lane shfl scan of degrees and ONE atomicAdd on a global cursor.
// (Round-5 k_scan was 460us at 0.29% occupancy - pure latency.)
__global__ void k_alloc(const int* __restrict__ degA, int* __restrict__ offA, int* __restrict__ curA,
                        const int* __restrict__ degB, int* __restrict__ offB, int* __restrict__ curB,
                        int* __restrict__ cursors) {
  int i = blockIdx.x * 256 + threadIdx.x;
  int lane = threadIdx.x & 63;
  bool act = i < NNODE;
#pragma unroll
  for (int which = 0; which < 2; ++which) {
    const int* deg = which ? degB : degA;
    int* off = which ? offB : offA;
    int* cur = which ? curB : curA;
    int d = act ? deg[i] : 0;
    int incl = d;
#pragma unroll
    for (int s = 1; s < 64; s <<= 1) {
      int v = __shfl_up(incl, s, 64);
      if (lane >= s) incl += v;
    }
    int base = 0;
    if (lane == 63) base = atomicAdd(&cursors[which], incl);
    base = __shfl(base, 63, 64);
    if (act) {
      int o = base + incl - d;
      off[i] = o;
      cur[i] = o;
    }
  }
}

__global__ void k_fill(const int* __restrict__ ei, const int* __restrict__ c2li,
                       int* __restrict__ curA, int* __restrict__ listA,
                       int* __restrict__ curB, int* __restrict__ listB) {
  int j = blockIdx.x * 256 + threadIdx.x;
  if (j < NEDGE) {
    int d = ei[2 * j + 1];
    int s = atomicAdd(&curA[d], 1);
    listA[s] = j;
  }
  if (j < HEDGE) {
    int jj = c2li[j];
    int sn = ei[2 * jj], dn = ei[2 * jj + 1];
    int s = atomicAdd(&curB[sn], 1);
    listB[s] = dn;
  }
}

// ---- per-node gather sum: aggr[n] = sum of emb rows of in-edges ----
__global__ void k_aggr_g(const int* __restrict__ off, const int* __restrict__ deg,
                         const int* __restrict__ list, const float* __restrict__ emb,
                         float* __restrict__ aggr) {
  int w = blockIdx.x * 4 + (threadIdx.x >> 6);
  int c = threadIdx.x & 63;
  if (w >= NNODE) return;
  int o = off[w], n = deg[w];
  float s = 0.f;
  for (int i = 0; i < n; ++i) {
    int e = list[o + i];
    s += emb[(size_t)e * 64 + c];
  }
  aggr[(size_t)w * 64 + c] = s;  // empty nodes -> 0 (they may be read via l2c_src)
}

// ---- per-node fused online LSE over emb[dst] rows of its c2l out-edges ----
__global__ void k_lse_g(const int* __restrict__ off, const int* __restrict__ deg,
                        const int* __restrict__ list, const float* __restrict__ emb,
                        float* __restrict__ lse) {
  int w = blockIdx.x * 4 + (threadIdx.x >> 6);
  int c = threadIdx.x & 63;
  if (w >= NNODE) return;
  int o = off[w], n = deg[w];
  if (n == 0) return;  // lse only ever read at nodes with c2l out-edges
  float m = -INFINITY, s = 0.f;
  for (int i = 0; i < n; ++i) {
    int d = list[o + i];
    float v = emb[(size_t)d * 64 + c];
    float nm = fmaxf(m, v);
    s = s * __expf(m - nm) + __expf(v - nm);
    m = nm;
  }
  lse[(size_t)w * 64 + c] = __logf(s) + m;  // s >= 1 here
}

// ======================= weight prep =======================
// Frag-ordered bf16 hi/lo. value = W[32s + 8*(lane>>4) + j][16c + (lane&15)].
// Elem offsets: l2c L1/L2/L3: 0/4096/8192; merge_W0: 12288 (K=128);
// merge_W L1/L2: 20480/24576; c2l L1/L2/L3: 28672/32768/36864. Total 40960.
__global__ void k_prepw(const float* __restrict__ l2cW, const float* __restrict__ mW0,
                        const float* __restrict__ mW, const float* __restrict__ c2lW,
                        unsigned short* __restrict__ WH, unsigned short* __restrict__ WL) {
  int tid = blockIdx.x * 256 + threadIdx.x;
  if (tid >= 40960) return;
  const float* src;
  int base;
  if (tid < 12288) {
    int m = tid / 4096; src = l2cW + m * 4096; base = m * 4096;
  } else if (tid < 20480) {
    src = mW0; base = 12288;
  } else if (tid < 28672) {
    int m = (tid - 20480) / 4096; src = mW + m * 4096; base = 20480 + m * 4096;
  } else {
    int m = (tid - 28672) / 4096; src = c2lW + m * 4096; base = 28672 + m * 4096;
  }
  int local = tid - base;
  int f = local >> 9;           // frag id = s*4+c
  int l = (local >> 3) & 63;    // lane
  int j = local & 7;            // elem
  int s = f >> 2, c = f & 3;
  int k = 32 * s + 8 * (l >> 4) + j;
  int col = 16 * c + (l & 15);
  float v = src[k * 64 + col];
  unsigned short hh = f2bf(v);
  WH[tid] = hh;
  WL[tid] = f2bf(v - bf2f(hh));
}

// ======================= MFMA MLP machinery =======================
// Wave-private LDS tile xs[16 rows][64 cols] f32, XOR-swizzled:
//   dword(row,col) = row*64 + (((col>>2) ^ row) & 15)*4 + (col & 3)

__device__ __forceinline__ void split8(float t0, float t1, float t2, float t3,
                                       float t4, float t5, float t6, float t7,
                                       bf16x8& ah, bf16x8& al) {
  unsigned short h;
  h = f2bf(t0); ah[0] = (short)h; al[0] = (short)f2bf(t0 - bf2f(h));
  h = f2bf(t1); ah[1] = (short)h; al[1] = (short)f2bf(t1 - bf2f(h));
  h = f2bf(t2); ah[2] = (short)h; al[2] = (short)f2bf(t2 - bf2f(h));
  h = f2bf(t3); ah[3] = (short)h; al[3] = (short)f2bf(t3 - bf2f(h));
  h = f2bf(t4); ah[4] = (short)h; al[4] = (short)f2bf(t4 - bf2f(h));
  h = f2bf(t5); ah[5] = (short)h; al[5] = (short)f2bf(t5 - bf2f(h));
  h = f2bf(t6); ah[6] = (short)h; al[6] = (short)f2bf(t6 - bf2f(h));
  h = f2bf(t7); ah[7] = (short)h; al[7] = (short)f2bf(t7 - bf2f(h));
}

// Split-bf16: acc += al*wh + ah*wl + ah*wh (misses only lo*lo ~ 2^-18).
template <int NS, bool RELU, bool FLIP>
__device__ __forceinline__ void mfma_layer(const float* xw, int lane,
                                           const unsigned short* __restrict__ wh_,
                                           const unsigned short* __restrict__ wl_,
                                           const float* __restrict__ bias, f32x4 (&acc)[4]) {
  int col15 = lane & 15, hq = lane >> 4;
#pragma unroll
  for (int c = 0; c < 4; ++c) {
    float bv = bias[16 * c + col15];
    acc[c] = (f32x4){bv, bv, bv, bv};
  }
#pragma unroll
  for (int s = 0; s < NS; ++s) {
    int flip = (FLIP && s >= NS / 2);
    int arow = flip ? (col15 ^ 1) : col15;
    int ks = flip ? (s - NS / 2) : s;
    const float* xr = xw + arow * 64;
    float4 A0 = *(const float4*)(xr + ((((8 * ks + 2 * hq + 0) ^ arow) & 15) << 2));
    float4 A1 = *(const float4*)(xr + ((((8 * ks + 2 * hq + 1) ^ arow) & 15) << 2));
    bf16x8 ah, al;
    split8(A0.x, A0.y, A0.z, A0.w, A1.x, A1.y, A1.z, A1.w, ah, al);
#pragma unroll
    for (int c = 0; c < 4; ++c) {
      const unsigned short* wo = wh_ + ((size_t)((s * 4 + c) * 64 + lane) * 8);
      const unsigned short* lo = wl_ + ((size_t)((s * 4 + c) * 64 + lane) * 8);
      bf16x8 wh = *(const bf16x8*)wo;
      bf16x8 wl = *(const bf16x8*)lo;
      acc[c] = __builtin_amdgcn_mfma_f32_16x16x32_bf16(al, wh, acc[c], 0, 0, 0);
      acc[c] = __builtin_amdgcn_mfma_f32_16x16x32_bf16(ah, wl, acc[c], 0, 0, 0);
      acc[c] = __builtin_amdgcn_mfma_f32_16x16x32_bf16(ah, wh, acc[c], 0, 0, 0);
    }
  }
  if (RELU) {
#pragma unroll
    for (int c = 0; c < 4; ++c)
#pragma unroll
      for (int r = 0; r < 4; ++r) acc[c][r] = fmaxf(acc[c][r], 0.f);
  }
}

__device__ __forceinline__ void commitA(float* xw, int lane, const f32x4 (&acc)[4]) {
  int col15 = lane & 15, hq = lane >> 4;
#pragma unroll
  for (int c = 0; c < 4; ++c)
#pragma unroll
    for (int r = 0; r < 4; ++r) {
      int row = 4 * hq + r, col = 16 * c + col15;
      xw[row * 64 + ((((col >> 2) ^ row) & 15) << 2) + (col & 3)] = acc[c][r];
    }
}

// ---- l2c: 3-layer MLP -> pair merge (K=128, flip) -> 2-layer MLP ----
__global__ void __launch_bounds__(256, 4)
k_l2c(const int* __restrict__ ei, const int* __restrict__ l2ci,
      const float* __restrict__ emb, const float* __restrict__ aggr,
      const unsigned short* __restrict__ WH, const unsigned short* __restrict__ WL,
      const float* __restrict__ l2cb, const float* __restrict__ mb0,
      const float* __restrict__ mb, float* __restrict__ out) {
  __shared__ float xs[4][1024];
  int lane = threadIdx.x & 63, w = threadIdx.x >> 6;
  float* xw = xs[w];
  int rbase = (blockIdx.x * 4 + w) * 16;
  int col15 = lane & 15, hq = lane >> 4;
  int rin = min(rbase + col15, HEDGE - 1);
  int j = l2ci[rin];
  int sN = ei[2 * j], dN = ei[2 * j + 1];
  const float* ap = aggr + (size_t)sN * 64 + 16 * hq;
  const float* ep = emb + (size_t)dN * 64 + 16 * hq;
#pragma unroll
  for (int q = 0; q < 4; ++q) {
    float4 a = *(const float4*)(ap + 4 * q);
    float4 e = *(const float4*)(ep + 4 * q);
    float4 v = {a.x - e.x, a.y - e.y, a.z - e.z, a.w - e.w};
    *(float4*)(xw + col15 * 64 + ((((4 * hq + q) ^ col15) & 15) << 2)) = v;
  }
  f32x4 acc[4];
  mfma_layer<2, true, false>(xw, lane, WH, WL, l2cb, acc);                     commitA(xw, lane, acc);
  mfma_layer<2, true, false>(xw, lane, WH + 4096, WL + 4096, l2cb + 64, acc);  commitA(xw, lane, acc);
  mfma_layer<2, false, false>(xw, lane, WH + 8192, WL + 8192, l2cb + 128, acc); commitA(xw, lane, acc);
  mfma_layer<4, true, true>(xw, lane, WH + 12288, WL + 12288, mb0, acc);       commitA(xw, lane, acc);
  mfma_layer<2, true, false>(xw, lane, WH + 20480, WL + 20480, mb, acc);       commitA(xw, lane, acc);
  mfma_layer<2, false, false>(xw, lane, WH + 24576, WL + 24576, mb + 64, acc);
  int jo[4];
#pragma unroll
  for (int r = 0; r < 4; ++r) {
    int rr = rbase + 4 * hq + r;
    jo[r] = (rr < HEDGE) ? l2ci[rr] : -1;
  }
#pragma unroll
  for (int c = 0; c < 4; ++c)
#pragma unroll
    for (int r = 0; r < 4; ++r)
      if (jo[r] >= 0) out[(size_t)jo[r] * 64 + 16 * c + col15] = acc[c][r];
}

// ---- c2l: 3-layer MLP on (lse[src] - e) ----
__global__ void __launch_bounds__(256, 4)
k_c2l(const int* __restrict__ ei, const int* __restrict__ c2li,
      const float* __restrict__ emb, const float* __restrict__ lse,
      const unsigned short* __restrict__ WH, const unsigned short* __restrict__ WL,
      const float* __restrict__ c2lb, float* __restrict__ out) {
  __shared__ float xs[4][1024];
  int lane = threadIdx.x & 63, w = threadIdx.x >> 6;
  float* xw = xs[w];
  int rbase = (blockIdx.x * 4 + w) * 16;
  int col15 = lane & 15, hq = lane >> 4;
  int rin = min(rbase + col15, HEDGE - 1);
  int j = c2li[rin];
  int sN = ei[2 * j], dN = ei[2 * j + 1];
  const float* ap = lse + (size_t)sN * 64 + 16 * hq;
  const float* ep = emb + (size_t)dN * 64 + 16 * hq;
#pragma unroll
  for (int q = 0; q < 4; ++q) {
    float4 a = *(const float4*)(ap + 4 * q);
    float4 e = *(const float4*)(ep + 4 * q);
    float4 v = {a.x - e.x, a.y - e.y, a.z - e.z, a.w - e.w};
    *(float4*)(xw + col15 * 64 + ((((4 * hq + q) ^ col15) & 15) << 2)) = v;
  }
  f32x4 acc[4];
  mfma_layer<2, true, false>(xw, lane, WH + 28672, WL + 28672, c2lb, acc);       commitA(xw, lane, acc);
  mfma_layer<2, true, false>(xw, lane, WH + 32768, WL + 32768, c2lb + 64, acc);  commitA(xw, lane, acc);
  mfma_layer<2, false, false>(xw, lane, WH + 36864, WL + 36864, c2lb + 128, acc);
  int jo[4];
#pragma unroll
  for (int r = 0; r < 4; ++r) {
    int rr = rbase + 4 * hq + r;
    jo[r] = (rr < HEDGE) ? c2li[rr] : -1;
  }
#pragma unroll
  for (int c = 0; c < 4; ++c)
#pragma unroll
    for (int r = 0; r < 4; ++r)
      if (jo[r] >= 0) out[(size_t)jo[r] * 64 + 16 * c + col15] = acc[c][r];
}

extern "C" void kernel_launch(void* const* d_in, const int* in_sizes, int n_in,
                              void* d_out, int out_size, void* d_ws, size_t ws_size,
                              hipStream_t stream) {
  const int* ei = (const int*)d_in[0];
  const int* l2ci = (const int*)d_in[1];
  const int* c2li = (const int*)d_in[2];
  const float* emb = (const float*)d_in[3];
  const float* l2cW = (const float*)d_in[4];
  const float* l2cb = (const float*)d_in[5];
  const float* c2lW = (const float*)d_in[6];
  const float* c2lb = (const float*)d_in[7];
  const float* mW0 = (const float*)d_in[8];
  const float* mb0 = (const float*)d_in[9];
  const float* mW = (const float*)d_in[10];
  const float* mb = (const float*)d_in[11];
  float* out = (float*)d_out;

  char* ws = (char*)d_ws;
  const size_t NB = (size_t)NNODE * 64 * 4;  // 51.2 MB per node-buffer
  float* aggr = (float*)ws;
  float* lse = (float*)(ws + NB);
  unsigned short* WH = (unsigned short*)(ws + 2 * NB);
  unsigned short* WL = WH + 40960;  // 163840 B total for weights
  char* p = ws + 2 * NB + 163840;
  int* degA = (int*)p; p += NNODE * 4;
  int* degB = (int*)p; p += NNODE * 4;
  int* cursors = (int*)p; p += 2 * 4;
  int* offA = (int*)p; p += NNODE * 4;
  int* offB = (int*)p; p += NNODE * 4;
  int* curA = (int*)p; p += NNODE * 4;
  int* curB = (int*)p; p += NNODE * 4;
  int* listA = (int*)p; p += (size_t)NEDGE * 4;
  int* listB = (int*)p; p += (size_t)HEDGE * 4;

  hipMemsetAsync(degA, 0, (2 * (size_t)NNODE + 2) * 4, stream);  // degA,degB,cursors

  dim3 B(256);
  int gE = (NEDGE + 255) / 256;
  k_deg<<<gE, B, 0, stream>>>(ei, c2li, degA, degB);
  k_alloc<<<(NNODE + 255) / 256, B, 0, stream>>>(degA, offA, curA, degB, offB, curB, cursors);
  k_fill<<<gE, B, 0, stream>>>(ei, c2li, curA, listA, curB, listB);
  k_prepw<<<160, B, 0, stream>>>(l2cW, mW0, mW, c2lW, WH, WL);
  int gN = (NNODE + 3) / 4;
  k_aggr_g<<<gN, B, 0, stream>>>(offA, degA, listA, emb, aggr);
  k_lse_g<<<gN, B, 0, stream>>>(offB, degB, listB, emb, lse);
  int gmlp = (HEDGE / 16 + 3) / 4;
  k_l2c<<<gmlp, B, 0, stream>>>(ei, l2ci, emb, aggr, WH, WL, l2cb, mb0, mb, out);
  k_c2l<<<gmlp, B, 0, stream>>>(ei, c2li, emb, lse, WH, WL, c2lb, out);
}

// Round 7
// 739.762 us; speedup vs baseline: 1.5971x; 1.0999x over previous
//
#include <hip/hip_runtime.h>
#include <math.h>

#define NNODE 200000
#define NEDGE 1000000
#define HEDGE 500000

typedef __attribute__((ext_vector_type(8))) short bf16x8;
typedef __attribute__((ext_vector_type(4))) float f32x4;

// ---- float <-> bf16 (RNE) ----
__device__ __forceinline__ unsigned short f2bf(float f) {
  unsigned u = __float_as_uint(f);
  unsigned r = (u + 0x7fffu + ((u >> 16) & 1u)) >> 16;
  return (unsigned short)r;
}
__device__ __forceinline__ float bf2f(unsigned short h) {
  return __uint_as_float(((unsigned)h) << 16);
}

// ======================= CSR build =======================
// A: all edges bucketed by dst (for aggr). B: c2l edges bucketed by src
// (for LSE); listB stores the edge's dst node (the emb row to read).
__global__ void k_deg(const int* __restrict__ ei, const int* __restrict__ c2li,
                      int* __restrict__ degA, int* __restrict__ degB) {
  int j = blockIdx.x * 256 + threadIdx.x;
  if (j < NEDGE) atomicAdd(&degA[ei[2 * j + 1]], 1);
  if (j < HEDGE) {
    int jj = c2li[j];
    atomicAdd(&degB[ei[2 * jj]], 1);
  }
}

// Wave-aggregated CSR range allocator: bucket ORDER is irrelevant for the
// gather kernels. One atomicAdd per wave on a global cursor.
__global__ void k_alloc(const int* __restrict__ degA, int* __restrict__ offA, int* __restrict__ curA,
                        const int* __restrict__ degB, int* __restrict__ offB, int* __restrict__ curB,
                        int* __restrict__ cursors) {
  int i = blockIdx.x * 256 + threadIdx.x;
  int lane = threadIdx.x & 63;
  bool act = i < NNODE;
#pragma unroll
  for (int which = 0; which < 2; ++which) {
    const int* deg = which ? degB : degA;
    int* off = which ? offB : offA;
    int* cur = which ? curB : curA;
    int d = act ? deg[i] : 0;
    int incl = d;
#pragma unroll
    for (int s = 1; s < 64; s <<= 1) {
      int v = __shfl_up(incl, s, 64);
      if (lane >= s) incl += v;
    }
    int base = 0;
    if (lane == 63) base = atomicAdd(&cursors[which], incl);
    base = __shfl(base, 63, 64);
    if (act) {
      int o = base + incl - d;
      off[i] = o;
      cur[i] = o;
    }
  }
}

__global__ void k_fill(const int* __restrict__ ei, const int* __restrict__ c2li,
                       int* __restrict__ curA, int* __restrict__ listA,
                       int* __restrict__ curB, int* __restrict__ listB) {
  int j = blockIdx.x * 256 + threadIdx.x;
  if (j < NEDGE) {
    int d = ei[2 * j + 1];
    int s = atomicAdd(&curA[d], 1);
    listA[s] = j;
  }
  if (j < HEDGE) {
    int jj = c2li[j];
    int sn = ei[2 * jj], dn = ei[2 * jj + 1];
    int s = atomicAdd(&curB[sn], 1);
    listB[s] = dn;
  }
}

// ---- guarded online-LSE pair merge (handles empty partials m=-inf) ----
__device__ __forceinline__ void lse_merge1(float& m, float& s, float mo, float so) {
  float nm = fmaxf(m, mo);
  if (nm == -INFINITY) return;  // both empty
  float ea = (m == -INFINITY) ? 0.f : __expf(m - nm);
  float eb = (mo == -INFINITY) ? 0.f : __expf(mo - nm);
  s = s * ea + so * eb;
  m = nm;
}

// ---- fused gather: aggr (task A) + lse (task B), one wave per node ----
// 4x16-lane groups per wave: group g owns edges i = g, g+4, ... giving 4
// independent list->emb load chains per wave (round-6 k_aggr_g had 1 chain,
// VALUBusy 7.8% = pure latency). Each lane loads float4 (16 lanes = 256B row).
// Cross-group combine via shfl_xor(16|32) butterfly.
__global__ void k_gather(const int* __restrict__ offA, const int* __restrict__ degA,
                         const int* __restrict__ listA,
                         const int* __restrict__ offB, const int* __restrict__ degB,
                         const int* __restrict__ listB,
                         const float* __restrict__ emb,
                         float* __restrict__ aggr, float* __restrict__ lse, int gN) {
  int lane = threadIdx.x & 63, wv = threadIdx.x >> 6;
  int g = lane >> 4, l16 = lane & 15;
  bool taskA = blockIdx.x < gN;
  int node = (taskA ? blockIdx.x : blockIdx.x - gN) * 4 + wv;
  if (node >= NNODE) return;
  if (taskA) {
    int o = offA[node], n = degA[node];
    float sx = 0.f, sy = 0.f, sz = 0.f, sw = 0.f;
    for (int i = g; i < n; i += 4) {
      int e = listA[o + i];
      float4 v = *(const float4*)(emb + (size_t)e * 64 + 4 * l16);
      sx += v.x; sy += v.y; sz += v.z; sw += v.w;
    }
#pragma unroll
    for (int mask = 16; mask <= 32; mask <<= 1) {
      sx += __shfl_xor(sx, mask, 64);
      sy += __shfl_xor(sy, mask, 64);
      sz += __shfl_xor(sz, mask, 64);
      sw += __shfl_xor(sw, mask, 64);
    }
    if (g == 0) {
      float4 v = {sx, sy, sz, sw};
      *(float4*)(aggr + (size_t)node * 64 + 4 * l16) = v;  // empty nodes -> 0
    }
  } else {
    int o = offB[node], n = degB[node];
    if (n == 0) return;  // lse only read at nodes with c2l out-edges
    float mx = -INFINITY, my = -INFINITY, mz = -INFINITY, mw = -INFINITY;
    float sx = 0.f, sy = 0.f, sz = 0.f, sw = 0.f;
    for (int i = g; i < n; i += 4) {
      int d = listB[o + i];
      float4 v = *(const float4*)(emb + (size_t)d * 64 + 4 * l16);
      float nm;
      nm = fmaxf(mx, v.x); sx = sx * __expf(mx - nm) + __expf(v.x - nm); mx = nm;
      nm = fmaxf(my, v.y); sy = sy * __expf(my - nm) + __expf(v.y - nm); my = nm;
      nm = fmaxf(mz, v.z); sz = sz * __expf(mz - nm) + __expf(v.z - nm); mz = nm;
      nm = fmaxf(mw, v.w); sw = sw * __expf(mw - nm) + __expf(v.w - nm); mw = nm;
    }
#pragma unroll
    for (int mask = 16; mask <= 32; mask <<= 1) {
      lse_merge1(mx, sx, __shfl_xor(mx, mask, 64), __shfl_xor(sx, mask, 64));
      lse_merge1(my, sy, __shfl_xor(my, mask, 64), __shfl_xor(sy, mask, 64));
      lse_merge1(mz, sz, __shfl_xor(mz, mask, 64), __shfl_xor(sz, mask, 64));
      lse_merge1(mw, sw, __shfl_xor(mw, mask, 64), __shfl_xor(sw, mask, 64));
    }
    if (g == 0) {
      float4 v = {__logf(sx) + mx, __logf(sy) + my, __logf(sz) + mz, __logf(sw) + mw};
      *(float4*)(lse + (size_t)node * 64 + 4 * l16) = v;
    }
  }
}

// ======================= weight prep =======================
// Frag-ordered bf16 hi/lo. value = W[32s + 8*(lane>>4) + j][16c + (lane&15)].
// Elem offsets: l2c L1/L2/L3: 0/4096/8192; merge_W0: 12288 (K=128);
// merge_W L1/L2: 20480/24576; c2l L1/L2/L3: 28672/32768/36864. Total 40960.
__global__ void k_prepw(const float* __restrict__ l2cW, const float* __restrict__ mW0,
                        const float* __restrict__ mW, const float* __restrict__ c2lW,
                        unsigned short* __restrict__ WH, unsigned short* __restrict__ WL) {
  int tid = blockIdx.x * 256 + threadIdx.x;
  if (tid >= 40960) return;
  const float* src;
  int base;
  if (tid < 12288) {
    int m = tid / 4096; src = l2cW + m * 4096; base = m * 4096;
  } else if (tid < 20480) {
    src = mW0; base = 12288;
  } else if (tid < 28672) {
    int m = (tid - 20480) / 4096; src = mW + m * 4096; base = 20480 + m * 4096;
  } else {
    int m = (tid - 28672) / 4096; src = c2lW + m * 4096; base = 28672 + m * 4096;
  }
  int local = tid - base;
  int f = local >> 9;           // frag id = s*4+c
  int l = (local >> 3) & 63;    // lane
  int j = local & 7;            // elem
  int s = f >> 2, c = f & 3;
  int k = 32 * s + 8 * (l >> 4) + j;
  int col = 16 * c + (l & 15);
  float v = src[k * 64 + col];
  unsigned short hh = f2bf(v);
  WH[tid] = hh;
  WL[tid] = f2bf(v - bf2f(hh));
}

// ======================= MFMA MLP machinery =======================
// Wave-private LDS tile xs[16 rows][64 cols] f32, XOR-swizzled:
//   dword(row,col) = row*64 + (((col>>2) ^ row) & 15)*4 + (col & 3)

__device__ __forceinline__ void split8(float t0, float t1, float t2, float t3,
                                       float t4, float t5, float t6, float t7,
                                       bf16x8& ah, bf16x8& al) {
  unsigned short h;
  h = f2bf(t0); ah[0] = (short)h; al[0] = (short)f2bf(t0 - bf2f(h));
  h = f2bf(t1); ah[1] = (short)h; al[1] = (short)f2bf(t1 - bf2f(h));
  h = f2bf(t2); ah[2] = (short)h; al[2] = (short)f2bf(t2 - bf2f(h));
  h = f2bf(t3); ah[3] = (short)h; al[3] = (short)f2bf(t3 - bf2f(h));
  h = f2bf(t4); ah[4] = (short)h; al[4] = (short)f2bf(t4 - bf2f(h));
  h = f2bf(t5); ah[5] = (short)h; al[5] = (short)f2bf(t5 - bf2f(h));
  h = f2bf(t6); ah[6] = (short)h; al[6] = (short)f2bf(t6 - bf2f(h));
  h = f2bf(t7); ah[7] = (short)h; al[7] = (short)f2bf(t7 - bf2f(h));
}

// Split-bf16: acc += al*wh + ah*wl + ah*wh (misses only lo*lo ~ 2^-18).
template <int NS, bool RELU, bool FLIP>
__device__ __forceinline__ void mfma_layer(const float* xw, int lane,
                                           const unsigned short* __restrict__ wh_,
                                           const unsigned short* __restrict__ wl_,
                                           const float* __restrict__ bias, f32x4 (&acc)[4]) {
  int col15 = lane & 15, hq = lane >> 4;
#pragma unroll
  for (int c = 0; c < 4; ++c) {
    float bv = bias[16 * c + col15];
    acc[c] = (f32x4){bv, bv, bv, bv};
  }
#pragma unroll
  for (int s = 0; s < NS; ++s) {
    int flip = (FLIP && s >= NS / 2);
    int arow = flip ? (col15 ^ 1) : col15;
    int ks = flip ? (s - NS / 2) : s;
    const float* xr = xw + arow * 64;
    float4 A0 = *(const float4*)(xr + ((((8 * ks + 2 * hq + 0) ^ arow) & 15) << 2));
    float4 A1 = *(const float4*)(xr + ((((8 * ks + 2 * hq + 1) ^ arow) & 15) << 2));
    bf16x8 ah, al;
    split8(A0.x, A0.y, A0.z, A0.w, A1.x, A1.y, A1.z, A1.w, ah, al);
#pragma unroll
    for (int c = 0; c < 4; ++c) {
      const unsigned short* wo = wh_ + ((size_t)((s * 4 + c) * 64 + lane) * 8);
      const unsigned short* lo = wl_ + ((size_t)((s * 4 + c) * 64 + lane) * 8);
      bf16x8 wh = *(const bf16x8*)wo;
      bf16x8 wl = *(const bf16x8*)lo;
      acc[c] = __builtin_amdgcn_mfma_f32_16x16x32_bf16(al, wh, acc[c], 0, 0, 0);
      acc[c] = __builtin_amdgcn_mfma_f32_16x16x32_bf16(ah, wl, acc[c], 0, 0, 0);
      acc[c] = __builtin_amdgcn_mfma_f32_16x16x32_bf16(ah, wh, acc[c], 0, 0, 0);
    }
  }
  if (RELU) {
#pragma unroll
    for (int c = 0; c < 4; ++c)
#pragma unroll
      for (int r = 0; r < 4; ++r) acc[c][r] = fmaxf(acc[c][r], 0.f);
  }
}

__device__ __forceinline__ void commitA(float* xw, int lane, const f32x4 (&acc)[4]) {
  int col15 = lane & 15, hq = lane >> 4;
#pragma unroll
  for (int c = 0; c < 4; ++c)
#pragma unroll
    for (int r = 0; r < 4; ++r) {
      int row = 4 * hq + r, col = 16 * c + col15;
      xw[row * 64 + ((((col >> 2) ^ row) & 15) << 2) + (col & 3)] = acc[c][r];
    }
}

// ---- l2c: 3-layer MLP -> pair merge (K=128, flip) -> 2-layer MLP ----
__global__ void __launch_bounds__(256, 4)
k_l2c(const int* __restrict__ ei, const int* __restrict__ l2ci,
      const float* __restrict__ emb, const float* __restrict__ aggr,
      const unsigned short* __restrict__ WH, const unsigned short* __restrict__ WL,
      const float* __restrict__ l2cb, const float* __restrict__ mb0,
      const float* __restrict__ mb, float* __restrict__ out) {
  __shared__ float xs[4][1024];
  int lane = threadIdx.x & 63, w = threadIdx.x >> 6;
  float* xw = xs[w];
  int rbase = (blockIdx.x * 4 + w) * 16;
  int col15 = lane & 15, hq = lane >> 4;
  int rin = min(rbase + col15, HEDGE - 1);
  int j = l2ci[rin];
  int sN = ei[2 * j], dN = ei[2 * j + 1];
  const float* ap = aggr + (size_t)sN * 64 + 16 * hq;
  const float* ep = emb + (size_t)dN * 64 + 16 * hq;
#pragma unroll
  for (int q = 0; q < 4; ++q) {
    float4 a = *(const float4*)(ap + 4 * q);
    float4 e = *(const float4*)(ep + 4 * q);
    float4 v = {a.x - e.x, a.y - e.y, a.z - e.z, a.w - e.w};
    *(float4*)(xw + col15 * 64 + ((((4 * hq + q) ^ col15) & 15) << 2)) = v;
  }
  f32x4 acc[4];
  mfma_layer<2, true, false>(xw, lane, WH, WL, l2cb, acc);                     commitA(xw, lane, acc);
  mfma_layer<2, true, false>(xw, lane, WH + 4096, WL + 4096, l2cb + 64, acc);  commitA(xw, lane, acc);
  mfma_layer<2, false, false>(xw, lane, WH + 8192, WL + 8192, l2cb + 128, acc); commitA(xw, lane, acc);
  mfma_layer<4, true, true>(xw, lane, WH + 12288, WL + 12288, mb0, acc);       commitA(xw, lane, acc);
  mfma_layer<2, true, false>(xw, lane, WH + 20480, WL + 20480, mb, acc);       commitA(xw, lane, acc);
  mfma_layer<2, false, false>(xw, lane, WH + 24576, WL + 24576, mb + 64, acc);
  int jo[4];
#pragma unroll
  for (int r = 0; r < 4; ++r) {
    int rr = rbase + 4 * hq + r;
    jo[r] = (rr < HEDGE) ? l2ci[rr] : -1;
  }
#pragma unroll
  for (int c = 0; c < 4; ++c)
#pragma unroll
    for (int r = 0; r < 4; ++r)
      if (jo[r] >= 0) out[(size_t)jo[r] * 64 + 16 * c + col15] = acc[c][r];
}

// ---- c2l: 3-layer MLP on (lse[src] - e) ----
__global__ void __launch_bounds__(256, 4)
k_c2l(const int* __restrict__ ei, const int* __restrict__ c2li,
      const float* __restrict__ emb, const float* __restrict__ lse,
      const unsigned short* __restrict__ WH, const unsigned short* __restrict__ WL,
      const float* __restrict__ c2lb, float* __restrict__ out) {
  __shared__ float xs[4][1024];
  int lane = threadIdx.x & 63, w = threadIdx.x >> 6;
  float* xw = xs[w];
  int rbase = (blockIdx.x * 4 + w) * 16;
  int col15 = lane & 15, hq = lane >> 4;
  int rin = min(rbase + col15, HEDGE - 1);
  int j = c2li[rin];
  int sN = ei[2 * j], dN = ei[2 * j + 1];
  const float* ap = lse + (size_t)sN * 64 + 16 * hq;
  const float* ep = emb + (size_t)dN * 64 + 16 * hq;
#pragma unroll
  for (int q = 0; q < 4; ++q) {
    float4 a = *(const float4*)(ap + 4 * q);
    float4 e = *(const float4*)(ep + 4 * q);
    float4 v = {a.x - e.x, a.y - e.y, a.z - e.z, a.w - e.w};
    *(float4*)(xw + col15 * 64 + ((((4 * hq + q) ^ col15) & 15) << 2)) = v;
  }
  f32x4 acc[4];
  mfma_layer<2, true, false>(xw, lane, WH + 28672, WL + 28672, c2lb, acc);       commitA(xw, lane, acc);
  mfma_layer<2, true, false>(xw, lane, WH + 32768, WL + 32768, c2lb + 64, acc);  commitA(xw, lane, acc);
  mfma_layer<2, false, false>(xw, lane, WH + 36864, WL + 36864, c2lb + 128, acc);
  int jo[4];
#pragma unroll
  for (int r = 0; r < 4; ++r) {
    int rr = rbase + 4 * hq + r;
    jo[r] = (rr < HEDGE) ? c2li[rr] : -1;
  }
#pragma unroll
  for (int c = 0; c < 4; ++c)
#pragma unroll
    for (int r = 0; r < 4; ++r)
      if (jo[r] >= 0) out[(size_t)jo[r] * 64 + 16 * c + col15] = acc[c][r];
}

extern "C" void kernel_launch(void* const* d_in, const int* in_sizes, int n_in,
                              void* d_out, int out_size, void* d_ws, size_t ws_size,
                              hipStream_t stream) {
  const int* ei = (const int*)d_in[0];
  const int* l2ci = (const int*)d_in[1];
  const int* c2li = (const int*)d_in[2];
  const float* emb = (const float*)d_in[3];
  const float* l2cW = (const float*)d_in[4];
  const float* l2cb = (const float*)d_in[5];
  const float* c2lW = (const float*)d_in[6];
  const float* c2lb = (const float*)d_in[7];
  const float* mW0 = (const float*)d_in[8];
  const float* mb0 = (const float*)d_in[9];
  const float* mW = (const float*)d_in[10];
  const float* mb = (const float*)d_in[11];
  float* out = (float*)d_out;

  char* ws = (char*)d_ws;
  const size_t NB = (size_t)NNODE * 64 * 4;  // 51.2 MB per node-buffer
  float* aggr = (float*)ws;
  float* lse = (float*)(ws + NB);
  unsigned short* WH = (unsigned short*)(ws + 2 * NB);
  unsigned short* WL = WH + 40960;  // 163840 B total for weights
  char* p = ws + 2 * NB + 163840;
  int* degA = (int*)p; p += NNODE * 4;
  int* degB = (int*)p; p += NNODE * 4;
  int* cursors = (int*)p; p += 2 * 4;
  int* offA = (int*)p; p += NNODE * 4;
  int* offB = (int*)p; p += NNODE * 4;
  int* curA = (int*)p; p += NNODE * 4;
  int* curB = (int*)p; p += NNODE * 4;
  int* listA = (int*)p; p += (size_t)NEDGE * 4;
  int* listB = (int*)p; p += (size_t)HEDGE * 4;

  hipMemsetAsync(degA, 0, (2 * (size_t)NNODE + 2) * 4, stream);  // degA,degB,cursors

  dim3 B(256);
  int gE = (NEDGE + 255) / 256;
  k_deg<<<gE, B, 0, stream>>>(ei, c2li, degA, degB);
  k_alloc<<<(NNODE + 255) / 256, B, 0, stream>>>(degA, offA, curA, degB, offB, curB, cursors);
  k_fill<<<gE, B, 0, stream>>>(ei, c2li, curA, listA, curB, listB);
  k_prepw<<<160, B, 0, stream>>>(l2cW, mW0, mW, c2lW, WH, WL);
  int gN = (NNODE + 3) / 4;
  k_gather<<<2 * gN, B, 0, stream>>>(offA, degA, listA, offB, degB, listB, emb, aggr, lse, gN);
  int gmlp = (HEDGE / 16 + 3) / 4;
  k_l2c<<<gmlp, B, 0, stream>>>(ei, l2ci, emb, aggr, WH, WL, l2cb, mb0, mb, out);
  k_c2l<<<gmlp, B, 0, stream>>>(ei, c2li, emb, lse, WH, WL, c2lb, out);
}